// Round 3
// baseline (168.029 us; speedup 1.0000x reference)
//
#include <hip/hip_runtime.h>
#include <hip/hip_bf16.h>
#include <math.h>

#define Bn  16
#define Ln  256
#define Wn  4
#define Hn  128
#define Nn  259          // L + W - 1
#define EPSF 1e-6f
#define PSTR 320         // padded per-(slice,batch) stride in partial arrays
#define X2AP_OFF (5 * Bn * PSTR)      // x1a_p size in floats
#define NBLK 400         // 5*5*16 blocks — all co-resident (see barrier note)

typedef float f32x4 __attribute__((ext_vector_type(4)));
typedef short s16x8 __attribute__((ext_vector_type(8)));

// Cross-phase partial sums in a module-scope device global (200 KB); every
// slot is written by exactly one thread before the grid barrier, then read.
__device__ float g_part[2 * X2AP_OFF];
// Grid barrier ticket counter. Monotonic ticket scheme => replay-safe across
// graph iterations with no reset: launch k's tickets are [k*400,(k+1)*400),
// every block waits for (k+1)*400.
__device__ int g_bar;

__device__ __forceinline__ unsigned short bfb(float x) {
    union { __hip_bfloat16 h; unsigned short u; } t;
    t.h = __float2bfloat16(x);
    return t.u;
}

// Single plain-launch kernel (graph-capture-safe; NO cooperative API):
//   Phase 1 (att): 64i x 64j att tile per block, batch b = blockIdx.z.
//     fp32->bf16 fused into LDS staging; row norms via mfma(a,a) Gram diagonal.
//     Partial row/col sums -> g_part slices (5 it slices x1a, 5 jt slices x2a).
//   soft grid barrier (safe: 400 blocks, LDS 36.4KB -> 4 blk/CU, and
//     __launch_bounds__(256,2) guarantees >=2 blk/CU by VGPR => capacity
//     >= 512 >= 400, all blocks co-resident, spin cannot deadlock)
//   Phase 2 (wp): 1024 chunks of 256 float4 outputs, grid-strided over the
//     400 blocks. out[b,l,h] = sum_{k<4} x[b,l+k,h] * a[b,l+k].
__global__ __launch_bounds__(256, 2) void fused(const float* __restrict__ x1,
                                                const float* __restrict__ x2,
                                                float* __restrict__ out) {
    __shared__ unsigned short As[64 * 136];   // x2 rows; stride 136 -> 2-way banks (free)
    __shared__ unsigned short Bs[64 * 136];   // x1 rows
    __shared__ float n2s[64], n1s[64];
    __shared__ float colpart[4 * 64];
    __shared__ float a_s[11];

    const int it = blockIdx.x, jt = blockIdx.y, b = blockIdx.z;
    const int i0 = it * 64, j0 = jt * 64;
    const int tid = threadIdx.x;

    const float* __restrict__ x1b = x1 + (size_t)b * Nn * Hn;
    const float* __restrict__ x2b = x2 + (size_t)b * Nn * Hn;

    // stage both tiles: 8 iters x (one float4 per lane per tile), convert to bf16
    #pragma unroll
    for (int iter = 0; iter < 8; ++iter) {
        const int idx = iter * 256 + tid;
        const int r = idx >> 5, c4 = idx & 31;
        float4 va = make_float4(0.f, 0.f, 0.f, 0.f), vb = va;
        if (i0 + r < Nn) va = ((const float4*)(x2b + (i0 + r) * Hn))[c4];
        if (j0 + r < Nn) vb = ((const float4*)(x1b + (j0 + r) * Hn))[c4];
        const unsigned long long pa =
            (unsigned long long)bfb(va.x)        | ((unsigned long long)bfb(va.y) << 16) |
            ((unsigned long long)bfb(va.z) << 32) | ((unsigned long long)bfb(va.w) << 48);
        const unsigned long long pb =
            (unsigned long long)bfb(vb.x)        | ((unsigned long long)bfb(vb.y) << 16) |
            ((unsigned long long)bfb(vb.z) << 32) | ((unsigned long long)bfb(vb.w) << 48);
        *((unsigned long long*)&As[r * 136 + c4 * 4]) = pa;
        *((unsigned long long*)&Bs[r * 136 + c4 * 4]) = pb;
    }
    __syncthreads();

    const int w = tid >> 6, lane = tid & 63;
    const int rsel = lane & 15, q = lane >> 4;

    f32x4 acc[4] = {{0,0,0,0}, {0,0,0,0}, {0,0,0,0}, {0,0,0,0}};
    f32x4 accA = {0,0,0,0}, accB = {0,0,0,0};     // Gram accumulators for norms
    const unsigned short* arow  = &As[(w * 16 + rsel) * 136 + q * 8];
    const unsigned short* bnrow = &Bs[(w * 16 + rsel) * 136 + q * 8];
    const unsigned short* brow  = &Bs[rsel * 136 + q * 8];
    #pragma unroll
    for (int s = 0; s < 4; ++s) {                 // K-steps of 32
        const s16x8 af = *((const s16x8*)(arow + s * 32));
        const s16x8 bn = *((const s16x8*)(bnrow + s * 32));
        accA = __builtin_amdgcn_mfma_f32_16x16x32_bf16(af, af, accA, 0, 0, 0);
        accB = __builtin_amdgcn_mfma_f32_16x16x32_bf16(bn, bn, accB, 0, 0, 0);
        #pragma unroll
        for (int t = 0; t < 4; ++t) {             // j-tiles of 16
            const s16x8 bf = *((const s16x8*)(brow + t * 16 * 136 + s * 32));
            acc[t] = __builtin_amdgcn_mfma_f32_16x16x32_bf16(af, bf, acc[t], 0, 0, 0);
        }
    }

    // Gram diagonal d lives at lane(col=d, row=d): q==d>>2, reg==d&3
    if (q == (rsel >> 2)) {
        n2s[w * 16 + rsel] = accA[rsel & 3];
        n1s[w * 16 + rsel] = accB[rsel & 3];
    }
    __syncthreads();   // n1s is read across waves below

    float rowacc[4] = {0.f, 0.f, 0.f, 0.f};
    #pragma unroll
    for (int t = 0; t < 4; ++t) {
        const int   j   = j0 + t * 16 + rsel;
        const bool  jv  = (j < Nn);
        const float n1v = n1s[t * 16 + rsel];
        float cp = 0.f;
        #pragma unroll
        for (int reg = 0; reg < 4; ++reg) {
            const int   i   = i0 + w * 16 + q * 4 + reg;
            const float e   = fmaf(-2.f, acc[t][reg], n2s[w * 16 + q * 4 + reg] + n1v + EPSF);
            // approx sqrt+rcp (~1 ulp each): error ~1e-6 relative, well inside tol
            const float att = ((i < Nn) && jv)
                ? __builtin_amdgcn_rcpf(__builtin_amdgcn_sqrtf(e) + 1.f) : 0.f;
            rowacc[reg] += att;
            cp          += att;
        }
        cp += __shfl_xor(cp, 16);                 // reduce over q (wave's 16 i)
        cp += __shfl_xor(cp, 32);
        if (q == 0) colpart[w * 64 + t * 16 + rsel] = cp;
    }
    // row sums (this block's 64 j): each i owned by exactly one wave -> plain store
    #pragma unroll
    for (int reg = 0; reg < 4; ++reg) {
        float rs = rowacc[reg];
        #pragma unroll
        for (int off = 8; off; off >>= 1) rs += __shfl_down(rs, off, 16);
        const int i = i0 + w * 16 + q * 4 + reg;
        if (rsel == 0 && i < Nn)
            g_part[X2AP_OFF + (jt * Bn + b) * PSTR + i] = rs;
    }
    __syncthreads();   // colpart complete
    if (tid < 64) {
        const int j = j0 + tid;
        if (j < Nn)
            g_part[(it * Bn + b) * PSTR + j] =
                colpart[tid] + colpart[64 + tid] + colpart[128 + tid] + colpart[192 + tid];
    }

    // ---- soft grid barrier (ticket-based, replay-safe, all blocks resident) ----
    __threadfence();                      // release this block's g_part stores
    __syncthreads();                      // all stores above issued+fenced
    if (tid == 0) {
        const int t = __hip_atomic_fetch_add(&g_bar, 1, __ATOMIC_ACQ_REL,
                                             __HIP_MEMORY_SCOPE_AGENT);
        const int target = (t / NBLK) * NBLK + NBLK;
        while (__hip_atomic_load(&g_bar, __ATOMIC_ACQUIRE,
                                 __HIP_MEMORY_SCOPE_AGENT) < target) {
            __builtin_amdgcn_s_sleep(2);
        }
    }
    __syncthreads();
    __threadfence();                      // acquire side: invalidate L1 before reads

    // ---- Phase 2: weighted pool. 1024 chunks grid-strided over 400 blocks ----
    const int lin = blockIdx.x + 5 * blockIdx.y + 25 * blockIdx.z;   // 0..399
    const int PER = Bn * Ln * Hn / 4;    // 131072 float4 per output half
    for (int blk = lin; blk < 1024; blk += NBLK) {
        __syncthreads();                 // protect a_s from previous chunk's readers
        const bool second = blk >= 512;
        const int eb = (second ? blk - 512 : blk) * 256;
        const int cb  = eb >> 13;
        const int l0 = (eb & 8191) >> 5;

        const float* x = second ? x2 : x1;
        const float* p = g_part + (second ? X2AP_OFF : 0) + cb * PSTR;
        if (tid < 11) {
            const int j = l0 + tid;      // <= 258, always written
            float s = 0.f;
            #pragma unroll
            for (int t = 0; t < 5; ++t) s += p[t * (Bn * PSTR) + j];
            a_s[tid] = s;
        }
        __syncthreads();

        const int e  = eb + tid;
        const int l  = (e & 8191) >> 5;
        const int h4 = e & 31;
        const float4* xb = (const float4*)(x + (size_t)cb * Nn * Hn);
        float4 accw = make_float4(0.f, 0.f, 0.f, 0.f);
        #pragma unroll
        for (int k = 0; k < Wn; ++k) {
            const float  av = a_s[l - l0 + k];
            const float4 xv = xb[(l + k) * (Hn / 4) + h4];
            accw.x += av * xv.x;
            accw.y += av * xv.y;
            accw.z += av * xv.z;
            accw.w += av * xv.w;
        }
        ((float4*)out)[(second ? PER : 0) + e] = accw;
    }
}

extern "C" void kernel_launch(void* const* d_in, const int* in_sizes, int n_in,
                              void* d_out, int out_size, void* d_ws, size_t ws_size,
                              hipStream_t stream) {
    const float* x1 = (const float*)d_in[0];
    const float* x2 = (const float*)d_in[1];
    (void)d_ws; (void)ws_size;            // workspace intentionally unused

    dim3 gridA(5, 5, Bn);                 // 64x64 tiles over 259x259, 16 batches
    fused<<<gridA, 256, 0, stream>>>(x1, x2, (float*)d_out);
}

// Round 4
// 85.103 us; speedup vs baseline: 1.9744x; 1.9744x over previous
//
#include <hip/hip_runtime.h>
#include <hip/hip_bf16.h>
#include <math.h>

#define Bn  16
#define Ln  256
#define Wn  4
#define Hn  128
#define Nn  259          // L + W - 1
#define EPSF 1e-6f
#define PSTR 320         // padded per-(slice,batch) stride in partial arrays
#define X2AP_OFF (5 * Bn * PSTR)      // x1a_p size in floats
#define NBLK 400         // 5*5*16 blocks — all co-resident (see barrier note)

typedef float f32x4 __attribute__((ext_vector_type(4)));
typedef short s16x8 __attribute__((ext_vector_type(8)));

// Cross-phase partial sums. ALL accesses are relaxed agent-scope atomics
// (sc1-coherent, bypassing the non-coherent per-XCD L2s), so no threadfence /
// cache-maintenance instructions are needed anywhere. Plain loads would also
// be wrong across graph replays (stale L2 lines from a prior iteration).
__device__ float g_part[2 * X2AP_OFF];
// Grid barrier ticket counter. Monotonic ticket scheme => replay-safe across
// graph iterations with no reset: launch k's tickets are [k*400,(k+1)*400),
// every block waits for (k+1)*400. Correctness proven in round 3 (passed).
__device__ int g_bar;

__device__ __forceinline__ unsigned short bfb(float x) {
    union { __hip_bfloat16 h; unsigned short u; } t;
    t.h = __float2bfloat16(x);
    return t.u;
}

// Single plain-launch kernel (graph-capture-safe; NO cooperative API):
//   Phase 1 (att): 64i x 64j att tile per block, batch b = blockIdx.z.
//     fp32->bf16 fused into LDS staging; row norms via mfma(a,a) Gram diagonal.
//     Partial row/col sums -> g_part slices (5 it slices x1a, 5 jt slices x2a).
//   Fence-free soft grid barrier (safe: 400 blocks, LDS 36.4KB -> 4 blk/CU,
//     __launch_bounds__(256,2) guarantees >=2 blk/CU by VGPR => capacity
//     >= 512 >= 400, all blocks co-resident, spin cannot deadlock).
//     __syncthreads() before arrival drains all waves' stores (compiler emits
//     s_waitcnt vmcnt(0) before s_barrier), and the stores are sc1-coherent,
//     so relaxed atomics suffice: no buffer_inv/buffer_wbl2 in the loop.
//   Phase 2 (wp): 1024 chunks of 256 float4 outputs, grid-strided over the
//     400 blocks. out[b,l,h] = sum_{k<4} x[b,l+k,h] * a[b,l+k].
__global__ __launch_bounds__(256, 2) void fused(const float* __restrict__ x1,
                                                const float* __restrict__ x2,
                                                float* __restrict__ out) {
    __shared__ unsigned short As[64 * 136];   // x2 rows; stride 136 -> 2-way banks (free)
    __shared__ unsigned short Bs[64 * 136];   // x1 rows
    __shared__ float n2s[64], n1s[64];
    __shared__ float colpart[4 * 64];
    __shared__ float a_s[11];

    const int it = blockIdx.x, jt = blockIdx.y, b = blockIdx.z;
    const int i0 = it * 64, j0 = jt * 64;
    const int tid = threadIdx.x;

    const float* __restrict__ x1b = x1 + (size_t)b * Nn * Hn;
    const float* __restrict__ x2b = x2 + (size_t)b * Nn * Hn;

    // stage both tiles: 8 iters x (one float4 per lane per tile), convert to bf16
    #pragma unroll
    for (int iter = 0; iter < 8; ++iter) {
        const int idx = iter * 256 + tid;
        const int r = idx >> 5, c4 = idx & 31;
        float4 va = make_float4(0.f, 0.f, 0.f, 0.f), vb = va;
        if (i0 + r < Nn) va = ((const float4*)(x2b + (i0 + r) * Hn))[c4];
        if (j0 + r < Nn) vb = ((const float4*)(x1b + (j0 + r) * Hn))[c4];
        const unsigned long long pa =
            (unsigned long long)bfb(va.x)        | ((unsigned long long)bfb(va.y) << 16) |
            ((unsigned long long)bfb(va.z) << 32) | ((unsigned long long)bfb(va.w) << 48);
        const unsigned long long pb =
            (unsigned long long)bfb(vb.x)        | ((unsigned long long)bfb(vb.y) << 16) |
            ((unsigned long long)bfb(vb.z) << 32) | ((unsigned long long)bfb(vb.w) << 48);
        *((unsigned long long*)&As[r * 136 + c4 * 4]) = pa;
        *((unsigned long long*)&Bs[r * 136 + c4 * 4]) = pb;
    }
    __syncthreads();

    const int w = tid >> 6, lane = tid & 63;
    const int rsel = lane & 15, q = lane >> 4;

    f32x4 acc[4] = {{0,0,0,0}, {0,0,0,0}, {0,0,0,0}, {0,0,0,0}};
    f32x4 accA = {0,0,0,0}, accB = {0,0,0,0};     // Gram accumulators for norms
    const unsigned short* arow  = &As[(w * 16 + rsel) * 136 + q * 8];
    const unsigned short* bnrow = &Bs[(w * 16 + rsel) * 136 + q * 8];
    const unsigned short* brow  = &Bs[rsel * 136 + q * 8];
    #pragma unroll
    for (int s = 0; s < 4; ++s) {                 // K-steps of 32
        const s16x8 af = *((const s16x8*)(arow + s * 32));
        const s16x8 bn = *((const s16x8*)(bnrow + s * 32));
        accA = __builtin_amdgcn_mfma_f32_16x16x32_bf16(af, af, accA, 0, 0, 0);
        accB = __builtin_amdgcn_mfma_f32_16x16x32_bf16(bn, bn, accB, 0, 0, 0);
        #pragma unroll
        for (int t = 0; t < 4; ++t) {             // j-tiles of 16
            const s16x8 bf = *((const s16x8*)(brow + t * 16 * 136 + s * 32));
            acc[t] = __builtin_amdgcn_mfma_f32_16x16x32_bf16(af, bf, acc[t], 0, 0, 0);
        }
    }

    // Gram diagonal d lives at lane(col=d, row=d): q==d>>2, reg==d&3
    if (q == (rsel >> 2)) {
        n2s[w * 16 + rsel] = accA[rsel & 3];
        n1s[w * 16 + rsel] = accB[rsel & 3];
    }
    __syncthreads();   // n1s is read across waves below

    float rowacc[4] = {0.f, 0.f, 0.f, 0.f};
    #pragma unroll
    for (int t = 0; t < 4; ++t) {
        const int   j   = j0 + t * 16 + rsel;
        const bool  jv  = (j < Nn);
        const float n1v = n1s[t * 16 + rsel];
        float cp = 0.f;
        #pragma unroll
        for (int reg = 0; reg < 4; ++reg) {
            const int   i   = i0 + w * 16 + q * 4 + reg;
            const float e   = fmaf(-2.f, acc[t][reg], n2s[w * 16 + q * 4 + reg] + n1v + EPSF);
            // approx sqrt+rcp (~1 ulp each): error ~1e-6 relative, well inside tol
            const float att = ((i < Nn) && jv)
                ? __builtin_amdgcn_rcpf(__builtin_amdgcn_sqrtf(e) + 1.f) : 0.f;
            rowacc[reg] += att;
            cp          += att;
        }
        cp += __shfl_xor(cp, 16);                 // reduce over q (wave's 16 i)
        cp += __shfl_xor(cp, 32);
        if (q == 0) colpart[w * 64 + t * 16 + rsel] = cp;
    }
    // row sums (this block's 64 j): each i owned by exactly one wave.
    // Coherent (sc1) relaxed store: visible device-wide once vmcnt-complete.
    #pragma unroll
    for (int reg = 0; reg < 4; ++reg) {
        float rs = rowacc[reg];
        #pragma unroll
        for (int off = 8; off; off >>= 1) rs += __shfl_down(rs, off, 16);
        const int i = i0 + w * 16 + q * 4 + reg;
        if (rsel == 0 && i < Nn)
            __hip_atomic_store(&g_part[X2AP_OFF + (jt * Bn + b) * PSTR + i], rs,
                               __ATOMIC_RELAXED, __HIP_MEMORY_SCOPE_AGENT);
    }
    __syncthreads();   // colpart complete
    if (tid < 64) {
        const int j = j0 + tid;
        if (j < Nn) {
            const float cs =
                colpart[tid] + colpart[64 + tid] + colpart[128 + tid] + colpart[192 + tid];
            __hip_atomic_store(&g_part[(it * Bn + b) * PSTR + j], cs,
                               __ATOMIC_RELAXED, __HIP_MEMORY_SCOPE_AGENT);
        }
    }

    // ---- fence-free soft grid barrier ----
    __syncthreads();   // drains every wave's stores (s_waitcnt vmcnt(0) before s_barrier)
    if (tid == 0) {
        asm volatile("s_waitcnt vmcnt(0)" ::: "memory");   // belt-and-suspenders
        const int t = __hip_atomic_fetch_add(&g_bar, 1, __ATOMIC_RELAXED,
                                             __HIP_MEMORY_SCOPE_AGENT);
        const int target = (t / NBLK) * NBLK + NBLK;
        // relaxed spin: no per-iteration cache ops; long backoff (~1.7us) keeps
        // the counter line uncongested so arriving fetch_adds aren't starved.
        while (__hip_atomic_load(&g_bar, __ATOMIC_RELAXED,
                                 __HIP_MEMORY_SCOPE_AGENT) < target) {
            __builtin_amdgcn_s_sleep(64);
        }
    }
    __syncthreads();

    // ---- Phase 2: weighted pool. 1024 chunks grid-strided over 400 blocks ----
    const int lin = blockIdx.x + 5 * blockIdx.y + 25 * blockIdx.z;   // 0..399
    const int PER = Bn * Ln * Hn / 4;    // 131072 float4 per output half
    for (int blk = lin; blk < 1024; blk += NBLK) {
        __syncthreads();                 // protect a_s from previous chunk's readers
        const bool second = blk >= 512;
        const int eb = (second ? blk - 512 : blk) * 256;
        const int cb  = eb >> 13;
        const int l0 = (eb & 8191) >> 5;

        const float* x = second ? x2 : x1;
        float* p = g_part + (second ? X2AP_OFF : 0) + cb * PSTR;
        if (tid < 11) {
            const int j = l0 + tid;      // <= 258, always written
            float s = 0.f;
            #pragma unroll
            for (int t = 0; t < 5; ++t)   // 5 independent coherent loads, pipelined
                s += __hip_atomic_load(&p[t * (Bn * PSTR) + j],
                                       __ATOMIC_RELAXED, __HIP_MEMORY_SCOPE_AGENT);
            a_s[tid] = s;
        }
        __syncthreads();

        const int e  = eb + tid;
        const int l  = (e & 8191) >> 5;
        const int h4 = e & 31;
        const float4* xb = (const float4*)(x + (size_t)cb * Nn * Hn);
        float4 accw = make_float4(0.f, 0.f, 0.f, 0.f);
        #pragma unroll
        for (int k = 0; k < Wn; ++k) {
            const float  av = a_s[l - l0 + k];
            const float4 xv = xb[(l + k) * (Hn / 4) + h4];
            accw.x += av * xv.x;
            accw.y += av * xv.y;
            accw.z += av * xv.z;
            accw.w += av * xv.w;
        }
        ((float4*)out)[(second ? PER : 0) + e] = accw;
    }
}

extern "C" void kernel_launch(void* const* d_in, const int* in_sizes, int n_in,
                              void* d_out, int out_size, void* d_ws, size_t ws_size,
                              hipStream_t stream) {
    const float* x1 = (const float*)d_in[0];
    const float* x2 = (const float*)d_in[1];
    (void)d_ws; (void)ws_size;            // workspace intentionally unused

    dim3 gridA(5, 5, Bn);                 // 64x64 tiles over 259x259, 16 batches
    fused<<<gridA, 256, 0, stream>>>(x1, x2, (float*)d_out);
}

// Round 5
// 71.597 us; speedup vs baseline: 2.3469x; 1.1886x over previous
//
#include <hip/hip_runtime.h>
#include <hip/hip_bf16.h>
#include <math.h>

#define Bn  16
#define Ln  256
#define Wn  4
#define Hn  128
#define Nn  259          // L + W - 1
#define EPSF 1e-6f
#define PSTR 320         // padded per-(slice,batch) stride in partial arrays
#define X1A_SZ (3 * Bn * PSTR)   // x1a region: 3 it-slices (128-row i tiles)

typedef float f32x4 __attribute__((ext_vector_type(4)));
typedef short s16x8 __attribute__((ext_vector_type(8)));

// Cross-kernel partial sums (plain accesses: the kernel boundary's
// release/acquire gives device-wide coherence — proven rounds 0/1).
// [x1a: 3 it-slices | x2a: 5 jt-slices], each slice Bn*PSTR floats.
// Every slot wp reads is rewritten by att2 every iteration (no stale reads
// across graph replays).
__device__ float g_part[8 * Bn * PSTR];

__device__ __forceinline__ unsigned short bfb(float x) {
    union { __hip_bfloat16 h; unsigned short u; } t;
    t.h = __float2bfloat16(x);
    return t.u;
}

// 128i x 64j att tile per block, batch b = blockIdx.z. Grid 3x5x16 = 240
// blocks <= 256 CUs -> exactly 1 block/CU: no 2-blocks-per-CU tail (the
// round-1 5x5x16=400 grid left 144 CUs carrying double VALU-staging load).
// fp32->bf16 fused into LDS staging; norms via mfma(a,a) Gram diagonals.
// Wave w owns i-rows [w*32, w*32+32) (2 subtiles) x all 64 j (4 subtiles).
// A-frag: lane holds A[m=lane&15][k=(lane>>4)*8+j]; C/D: col=lane&15,
// row=(lane>>4)*4+reg  (HW-verified mapping, carried from round-1 kernel).
__global__ __launch_bounds__(256) void att2(const float* __restrict__ x1,
                                            const float* __restrict__ x2) {
    __shared__ unsigned short As[128 * 136];  // x2 rows; stride 136 -> 2-way banks (free)
    __shared__ unsigned short Bs[64 * 136];   // x1 rows
    __shared__ float n2s[128], n1s[64];
    __shared__ float colpart[4 * 64];

    const int it = blockIdx.x, jt = blockIdx.y, b = blockIdx.z;
    const int i0 = it * 128, j0 = jt * 64;
    const int tid = threadIdx.x;

    const float* __restrict__ x1b = x1 + (size_t)b * Nn * Hn;
    const float* __restrict__ x2b = x2 + (size_t)b * Nn * Hn;

    // stage As (x2, 128 rows): 16 iters x one float4 per lane, convert to bf16
    #pragma unroll
    for (int iter = 0; iter < 16; ++iter) {
        const int idx = iter * 256 + tid;
        const int r = idx >> 5, c4 = idx & 31;
        float4 v = make_float4(0.f, 0.f, 0.f, 0.f);
        if (i0 + r < Nn) v = ((const float4*)(x2b + (i0 + r) * Hn))[c4];
        const unsigned long long p =
            (unsigned long long)bfb(v.x)        | ((unsigned long long)bfb(v.y) << 16) |
            ((unsigned long long)bfb(v.z) << 32) | ((unsigned long long)bfb(v.w) << 48);
        *((unsigned long long*)&As[r * 136 + c4 * 4]) = p;
    }
    // stage Bs (x1, 64 rows): 8 iters
    #pragma unroll
    for (int iter = 0; iter < 8; ++iter) {
        const int idx = iter * 256 + tid;
        const int r = idx >> 5, c4 = idx & 31;
        float4 v = make_float4(0.f, 0.f, 0.f, 0.f);
        if (j0 + r < Nn) v = ((const float4*)(x1b + (j0 + r) * Hn))[c4];
        const unsigned long long p =
            (unsigned long long)bfb(v.x)        | ((unsigned long long)bfb(v.y) << 16) |
            ((unsigned long long)bfb(v.z) << 32) | ((unsigned long long)bfb(v.w) << 48);
        *((unsigned long long*)&Bs[r * 136 + c4 * 4]) = p;
    }
    __syncthreads();

    const int w = tid >> 6, lane = tid & 63;
    const int rsel = lane & 15, q = lane >> 4;

    f32x4 acc[2][4] = {{{0,0,0,0},{0,0,0,0},{0,0,0,0},{0,0,0,0}},
                       {{0,0,0,0},{0,0,0,0},{0,0,0,0},{0,0,0,0}}};
    f32x4 accA0 = {0,0,0,0}, accA1 = {0,0,0,0}, accB = {0,0,0,0};
    const unsigned short* a0row = &As[(w * 32 + rsel) * 136 + q * 8];
    const unsigned short* a1row = &As[(w * 32 + 16 + rsel) * 136 + q * 8];
    const unsigned short* bnrow = &Bs[(w * 16 + rsel) * 136 + q * 8];
    const unsigned short* brow  = &Bs[rsel * 136 + q * 8];
    #pragma unroll
    for (int s = 0; s < 4; ++s) {                 // K-steps of 32
        const s16x8 af0 = *((const s16x8*)(a0row + s * 32));
        const s16x8 af1 = *((const s16x8*)(a1row + s * 32));
        const s16x8 bn  = *((const s16x8*)(bnrow + s * 32));
        accA0 = __builtin_amdgcn_mfma_f32_16x16x32_bf16(af0, af0, accA0, 0, 0, 0);
        accA1 = __builtin_amdgcn_mfma_f32_16x16x32_bf16(af1, af1, accA1, 0, 0, 0);
        accB  = __builtin_amdgcn_mfma_f32_16x16x32_bf16(bn,  bn,  accB,  0, 0, 0);
        #pragma unroll
        for (int t = 0; t < 4; ++t) {             // j-tiles of 16
            const s16x8 bf = *((const s16x8*)(brow + t * 16 * 136 + s * 32));
            acc[0][t] = __builtin_amdgcn_mfma_f32_16x16x32_bf16(af0, bf, acc[0][t], 0, 0, 0);
            acc[1][t] = __builtin_amdgcn_mfma_f32_16x16x32_bf16(af1, bf, acc[1][t], 0, 0, 0);
        }
    }

    // Gram diagonal d lives at lane(col=d, row=d): q==d>>2, reg==d&3
    if (q == (rsel >> 2)) {
        n2s[w * 32 + rsel]      = accA0[rsel & 3];
        n2s[w * 32 + 16 + rsel] = accA1[rsel & 3];
        n1s[w * 16 + rsel]      = accB[rsel & 3];
    }
    __syncthreads();   // n1s is read across waves below

    float rowacc[2][4] = {{0.f,0.f,0.f,0.f},{0.f,0.f,0.f,0.f}};
    #pragma unroll
    for (int t = 0; t < 4; ++t) {
        const int   j   = j0 + t * 16 + rsel;
        const bool  jv  = (j < Nn);
        const float n1v = n1s[t * 16 + rsel];
        float cp = 0.f;
        #pragma unroll
        for (int u = 0; u < 2; ++u) {
            #pragma unroll
            for (int reg = 0; reg < 4; ++reg) {
                const int   i   = i0 + w * 32 + u * 16 + q * 4 + reg;
                const float n2v = n2s[w * 32 + u * 16 + q * 4 + reg];
                const float e   = fmaf(-2.f, acc[u][t][reg], n2v + n1v + EPSF);
                // approx sqrt+rcp (~1 ulp each): error well inside tolerance
                const float att = ((i < Nn) && jv)
                    ? __builtin_amdgcn_rcpf(__builtin_amdgcn_sqrtf(e) + 1.f) : 0.f;
                rowacc[u][reg] += att;
                cp             += att;
            }
        }
        cp += __shfl_xor(cp, 16);                 // reduce over q (16 i per group)
        cp += __shfl_xor(cp, 32);
        if (q == 0) colpart[w * 64 + t * 16 + rsel] = cp;   // wave's 32-i sum
    }
    // row sums (this block's 64 j): each i owned by exactly one (wave,u)
    #pragma unroll
    for (int u = 0; u < 2; ++u) {
        #pragma unroll
        for (int reg = 0; reg < 4; ++reg) {
            float rs = rowacc[u][reg];
            #pragma unroll
            for (int off = 8; off; off >>= 1) rs += __shfl_down(rs, off, 16);
            const int i = i0 + w * 32 + u * 16 + q * 4 + reg;
            if (rsel == 0 && i < Nn)
                g_part[X1A_SZ + (jt * Bn + b) * PSTR + i] = rs;
        }
    }
    __syncthreads();   // colpart complete
    if (tid < 64) {
        const int j = j0 + tid;
        if (j < Nn)
            g_part[(it * Bn + b) * PSTR + j] =
                colpart[tid] + colpart[64 + tid] + colpart[128 + tid] + colpart[192 + tid];
    }
}

// out[b,l,h] = sum_{k<4} x[b,l+k,h] * a[b,l+k].
// a = sum of 3 it-slices (x1 half) or 5 jt-slices (x2 half).
// Block covers 256 consecutive float4 = 8 l values of one (half,b); needs
// a[b, l0..l0+10] -> reduce the partials once into LDS.
__global__ __launch_bounds__(256) void wp_kernel(const float* __restrict__ x1,
                                                 const float* __restrict__ x2,
                                                 float* __restrict__ out) {
    __shared__ float a_s[11];
    const int PER = Bn * Ln * Hn / 4;    // 131072 float4 per output half
    const int blk = blockIdx.x;
    const bool second = blk >= 512;
    const int eb = (second ? blk - 512 : blk) * 256;
    const int b  = eb >> 13;
    const int l0 = (eb & 8191) >> 5;

    const float* x = second ? x2 : x1;
    const float* p = g_part + (second ? X1A_SZ : 0) + b * PSTR;
    if (threadIdx.x < 11) {
        const int j = l0 + threadIdx.x;          // <= 258, always written
        float s = p[j] + p[Bn * PSTR + j] + p[2 * (Bn * PSTR) + j];
        if (second) s += p[3 * (Bn * PSTR) + j] + p[4 * (Bn * PSTR) + j];
        a_s[threadIdx.x] = s;
    }
    __syncthreads();

    const int e  = eb + threadIdx.x;
    const int l  = (e & 8191) >> 5;
    const int h4 = e & 31;
    const float4* xb = (const float4*)(x + (size_t)b * Nn * Hn);
    float4 acc = make_float4(0.f, 0.f, 0.f, 0.f);
    #pragma unroll
    for (int k = 0; k < Wn; ++k) {
        const float  av = a_s[l - l0 + k];
        const float4 xv = xb[(l + k) * (Hn / 4) + h4];
        acc.x += av * xv.x;
        acc.y += av * xv.y;
        acc.z += av * xv.z;
        acc.w += av * xv.w;
    }
    ((float4*)out)[(second ? PER : 0) + e] = acc;
}

extern "C" void kernel_launch(void* const* d_in, const int* in_sizes, int n_in,
                              void* d_out, int out_size, void* d_ws, size_t ws_size,
                              hipStream_t stream) {
    const float* x1 = (const float*)d_in[0];
    const float* x2 = (const float*)d_in[1];
    (void)d_ws; (void)ws_size;            // workspace intentionally unused

    dim3 gridA(3, 5, Bn);                 // 128x64 tiles over 259x259, 16 batches
    att2<<<gridA, 256, 0, stream>>>(x1, x2);

    wp_kernel<<<1024, 256, 0, stream>>>(x1, x2, (float*)d_out);
}